// Round 7
// baseline (190.980 us; speedup 1.0000x reference)
//
#include <hip/hip_runtime.h>

typedef __bf16 bf16_t;
typedef __bf16 bf16x2 __attribute__((ext_vector_type(2)));
typedef __bf16 bf16x8 __attribute__((ext_vector_type(8)));
typedef float f32x4 __attribute__((ext_vector_type(4)));
typedef unsigned u32;
typedef unsigned u32x4 __attribute__((ext_vector_type(4)));

#define N_PIX 4096
#define CFEAT 256
#define CKEY 32
#define NBATCH 4

#if __has_builtin(__builtin_amdgcn_exp2f)
#define EXP2(x) __builtin_amdgcn_exp2f(x)
#else
#define EXP2(x) exp2f(x)
#endif

static __device__ __forceinline__ f32x4 mfma16(bf16x8 a, bf16x8 b, f32x4 c) {
    return __builtin_amdgcn_mfma_f32_16x16x32_bf16(a, b, c, 0, 0, 0);
}

// async global->LDS, 16B per lane; LDS dest = wave-uniform base + lane*16
static __device__ __forceinline__ void glds16(const void* g, void* l) {
    __builtin_amdgcn_global_load_lds(
        (const __attribute__((address_space(1))) void*)g,
        (__attribute__((address_space(3))) void*)l, 16, 0, 0);
}

// pack two f32 -> one dword of 2 bf16 (v_cvt_pk_bf16_f32)
static __device__ __forceinline__ u32 pk2(float lo, float hi) {
    bf16x2 t; t[0] = (bf16_t)lo; t[1] = (bf16_t)hi;
    return __builtin_bit_cast(u32, t);
}

// 4-group transpose step (T12)
static __device__ __forceinline__ void xpose4(u32 &x, u32 &y) {
#if __has_builtin(__builtin_amdgcn_permlane32_swap) && __has_builtin(__builtin_amdgcn_permlane16_swap)
    auto r32 = __builtin_amdgcn_permlane32_swap(x, y, false, false);
    auto r16 = __builtin_amdgcn_permlane16_swap(r32[0], r32[1], false, false);
    x = r16[0]; y = r16[1];
#else
    const int lane = threadIdx.x & 63;
    const int g = lane >> 4, ln = lane & 15;
    const int i0 = ln + ((g & 1) << 5);
    const int i2 = i0 + 16;
    u32 xs0 = (u32)__shfl((int)x, i0), ys0 = (u32)__shfl((int)y, i0);
    u32 xs2 = (u32)__shfl((int)x, i2), ys2 = (u32)__shfl((int)y, i2);
    x = (g < 2) ? xs0 : ys0;
    y = (g < 2) ? xs2 : ys2;
#endif
}

// S^T tile (32 j x 16 i) -> exp2 -> single in-register P B-fragment.
// l-sum partial folded into accsum via ones-MFMA.
static __device__ __forceinline__ void softmax_tile32(
    const bf16x8 kf[2], bf16x8 qf, bf16x8 ones,
    f32x4 &accsum, bf16x8 &pa0)
{
    f32x4 zero = {0.f, 0.f, 0.f, 0.f};
    f32x4 st[2];
#pragma unroll
    for (int jt = 0; jt < 2; ++jt) st[jt] = mfma16(kf[jt], qf, zero);
    float ex[8];
#pragma unroll
    for (int jt = 0; jt < 2; ++jt)
#pragma unroll
        for (int r = 0; r < 4; ++r) ex[jt * 4 + r] = EXP2(st[jt][r]);
    u32 a0 = pk2(ex[0], ex[1]), a1 = pk2(ex[2], ex[3]);
    u32 b0 = pk2(ex[4], ex[5]), b1 = pk2(ex[6], ex[7]);
    xpose4(a0, b0); xpose4(a1, b1);
    u32x4 w0 = {a0, a1, b0, b1};
    pa0 = __builtin_bit_cast(bf16x8, w0);
    accsum = mfma16(ones, pa0, accsum);   // rows all = 32-j partial row-sum
}

// ---------------------------------------------------------------------------
// proj_kernel (R4-verified): Qt/Kt (transposed bf16, Q pre-scaled log2e) and
// V (bf16 [c][n]).
//   blocks [0,256):    Q  (xt = id&63, b = id>>6)   — from conditions
//   blocks [256,512):  K  (same decode)             — from features
//   blocks [512,1024): V  (xt = id&127, b = id>>7)  — from features.
// ---------------------------------------------------------------------------
__global__ __launch_bounds__(256) void proj_kernel(
    const float* __restrict__ Wq, const float* __restrict__ bq, const float* __restrict__ cond,
    const float* __restrict__ Wk, const float* __restrict__ bk, const float* __restrict__ feat,
    const float* __restrict__ Wv, const float* __restrict__ bv,
    bf16_t* __restrict__ Qt, bf16_t* __restrict__ Kt, bf16_t* __restrict__ Vv)
{
    __shared__ __attribute__((aligned(16))) bf16_t T[64][40];  // QK repack, +8 pad
    const int lane = threadIdx.x & 63, wave = threadIdx.x >> 6;
    const int g = lane >> 4, ln = lane & 15;
    const int bid = blockIdx.x;
    f32x4 zero = {0.f, 0.f, 0.f, 0.f};

    if (bid < 512) {
        const bool isK = (bid >= 256);
        const int idx = bid & 255;
        const int xt = idx & 63;
        const int b  = idx >> 6;
        const float* W    = isK ? Wk : Wq;
        const float* bias = isK ? bk : bq;
        const float* X  = (isK ? feat : cond) + (size_t)b * CFEAT * N_PIX;
        bf16_t*      Yt = (isK ? Kt : Qt) + (size_t)b * N_PIX * CKEY;
        const float qscale = isK ? 1.0f : 1.4426950408889634f;  // log2(e) into Q

        const int m_base = (wave & 1) * 16;
        const int n_loc  = (wave >> 1) * 32;
        const int n_base = xt * 64 + n_loc;

        f32x4 acc[2] = {zero, zero};
        for (int k0 = 0; k0 < CFEAT; k0 += 32) {
            bf16x8 a;
            const float* wp = W + (size_t)(m_base + ln) * CFEAT + k0 + g * 8;
#pragma unroll
            for (int j = 0; j < 8; ++j) a[j] = (bf16_t)wp[j];
#pragma unroll
            for (int nt = 0; nt < 2; ++nt) {
                const float* xp = X + (size_t)(k0 + g * 8) * N_PIX + n_base + nt * 16 + ln;
                bf16x8 bfr;
#pragma unroll
                for (int j = 0; j < 8; ++j) bfr[j] = (bf16_t)xp[(size_t)j * N_PIX];
                acc[nt] = mfma16(a, bfr, acc[nt]);
            }
        }
#pragma unroll
        for (int nt = 0; nt < 2; ++nt)
#pragma unroll
            for (int r = 0; r < 4; ++r) {
                const int ck = m_base + g * 4 + r;
                T[n_loc + nt * 16 + ln][ck] = (bf16_t)((acc[nt][r] + bias[ck]) * qscale);
            }
        __syncthreads();
        const int n  = threadIdx.x >> 2;
        const int sg = threadIdx.x & 3;
        bf16x8 row = *(const bf16x8*)&T[n][sg * 8];
        *(bf16x8*)&Yt[(size_t)(xt * 64 + n) * CKEY + sg * 8] = row;
    } else {
        const int idx = bid - 512;
        const int xt = idx & 127;
        const int b  = idx >> 7;
        const int n_base = xt * 32;
        const int c_wave = wave * 64;
        const float* Xb = feat + (size_t)b * CFEAT * N_PIX;
        bf16_t*      Vb = Vv + (size_t)b * CFEAT * N_PIX;

        f32x4 acc[4][2];
#pragma unroll
        for (int mt = 0; mt < 4; ++mt) { acc[mt][0] = zero; acc[mt][1] = zero; }

        for (int k0 = 0; k0 < CFEAT; k0 += 32) {
            bf16x8 bfr[2];
#pragma unroll
            for (int nt = 0; nt < 2; ++nt) {
                const float* xp = Xb + (size_t)(k0 + g * 8) * N_PIX + n_base + nt * 16 + ln;
#pragma unroll
                for (int j = 0; j < 8; ++j) bfr[nt][j] = (bf16_t)xp[(size_t)j * N_PIX];
            }
#pragma unroll
            for (int mt = 0; mt < 4; ++mt) {
                const float* wp = Wv + (size_t)(c_wave + mt * 16 + ln) * CFEAT + k0 + g * 8;
                bf16x8 a;
#pragma unroll
                for (int j = 0; j < 8; ++j) a[j] = (bf16_t)wp[j];
                acc[mt][0] = mfma16(a, bfr[0], acc[mt][0]);
                acc[mt][1] = mfma16(a, bfr[1], acc[mt][1]);
            }
        }
#pragma unroll
        for (int mt = 0; mt < 4; ++mt)
#pragma unroll
            for (int nt = 0; nt < 2; ++nt)
#pragma unroll
                for (int r = 0; r < 4; ++r) {
                    const int m = c_wave + mt * 16 + g * 4 + r;
                    const int n = n_base + nt * 16 + ln;
                    Vb[(size_t)m * N_PIX + n] = (bf16_t)(acc[mt][nt][r] + bv[m]);
                }
    }
}

// ---------------------------------------------------------------------------
// pv v4: 4-wave producer/consumer block sized for 2 blocks/CU.
//   - block = 256c x 32i, j-tile 32, 128 iters. waves 0-1 (sm): softmax for
//     16i each -> P[32i][32j] ping-pong LDS (64-B rows: naturally 8/bank-
//     uniform for b128 read AND write — no swizzle needed).
//   - all 4 waves: PV on a private 64c slice (4 V-frag + 2 P-frag reads,
//     8 MFMA per iter).
//   - ring-4 V (4 x 16KB, linear [c][32j]), stage dist 2 (4 glds16/thread),
//     K prefetch dist 2 (ping-pong regs), single barrier/iter, counted
//     fences: sm vmcnt(6) (2 K + 4 stage in flight), pv vmcnt(4).
//   - LDS total 68.1 KB -> 2 blocks/CU; grid (128,4) = 512 = exactly 2/CU:
//     co-resident block hides this block's fence/barrier stalls.
// ---------------------------------------------------------------------------
__global__ __launch_bounds__(256, 2) void pv_kernel(
    const bf16_t* __restrict__ Qt, const bf16_t* __restrict__ Kt,
    const bf16_t* __restrict__ V,
    const float* __restrict__ features, const float* __restrict__ gamma,
    float* __restrict__ out)
{
    __shared__ __attribute__((aligned(16))) bf16_t Vlds[4][8192];  // 4 x 16KB
    __shared__ __attribute__((aligned(16))) bf16_t Plds[2][1024];  // 2 x 2KB
    __shared__ float Llds[32];

    const int lane = threadIdx.x & 63, wave = threadIdx.x >> 6;  // 0..3
    const int g = lane >> 4, ln = lane & 15;
    const int b = blockIdx.y;
    const int i_base = blockIdx.x * 32;
    const bool sm = (wave < 2);

    const bf16_t* Qb = Qt + (size_t)b * N_PIX * CKEY;
    const bf16_t* Kb = Kt + (size_t)b * N_PIX * CKEY;
    const bf16_t* Vb = V + (size_t)b * CFEAT * N_PIX;

    // staging: tile = 256c x 32j = 1024 x 16B slots; thread q-th call loads
    // slot s = q*256 + wave*64 + lane -> c = s>>2, j-chunk = s&3 (linear).
    const bf16_t* vgp[4];
#pragma unroll
    for (int q = 0; q < 4; ++q) {
        const int s = q * 256 + wave * 64 + lane;
        vgp[q] = Vb + (size_t)(s >> 2) * N_PIX + (s & 3) * 8;
    }

#define STAGE(BUF, JOFF)                                                     \
    { _Pragma("unroll") for (int q = 0; q < 4; ++q)                          \
        glds16(vgp[q] + (JOFF), &Vlds[BUF][(q * 256 + wave * 64) * 8]); }

#define LOADK(DST, JQ)                                                       \
    { _Pragma("unroll") for (int jt = 0; jt < 2; ++jt)                       \
        DST[jt] = *(const bf16x8*)&Kb[(size_t)((JQ) + jt * 16 + ln) * CKEY + g * 8]; }

    // P layout [i=32][j=32] bf16 (64-B rows). sm wave w writes i = w*16+ln,
    // j = g*8..+7: one b128 store; PV reads same pattern.
#define PWRITE(SLOT, PA0)                                                    \
    { *(bf16x8*)&Plds[SLOT][(wave * 16 + ln) * 32 + g * 8] = PA0; }

    bf16x8 qf = {};
    if (sm) qf = *(const bf16x8*)&Qb[(size_t)(i_base + wave * 16 + ln) * CKEY + g * 8];

    bf16x8 ones;
#pragma unroll
    for (int j = 0; j < 8; ++j) ones[j] = (bf16_t)1.0f;

    f32x4 zero = {0.f, 0.f, 0.f, 0.f};
    f32x4 acc[4][2];
#pragma unroll
    for (int ct = 0; ct < 4; ++ct) { acc[ct][0] = zero; acc[ct][1] = zero; }
    f32x4 accsum = zero;

    bf16x8 kfA[2], kfB[2];

    // ---------------- prologue: P(0); stage V(0),V(1); kfA = K(1) ----------
    if (sm) LOADK(kfA, 0);
    asm volatile("" ::: "memory");
    STAGE(0, 0);
    STAGE(1, 32);
    if (sm) {
        bf16x8 pa0;
        softmax_tile32(kfA, qf, ones, accsum, pa0);
        PWRITE(0, pa0);
        LOADK(kfA, 32);
    }
    __syncthreads();   // prologue-only full drain (vm + lgkm)

// iter n: read V(n)+P(n) frags; sm: issue K(n+2), softmax K(n+1)->P(n+1);
// all: stage V(n+2); fence (sm vmcnt(6) / pv vmcnt(4)) + lgkmcnt(0) +
// barrier; PV(n) MFMAs.
#define PV_ITER(NN, KU, KN)                                                  \
  {                                                                          \
    const int nn = (NN);                                                     \
    const bf16_t* Vt = &Vlds[nn & 3][0];                                     \
    bf16x8 vf[4];                                                            \
    _Pragma("unroll")                                                        \
    for (int ct = 0; ct < 4; ++ct)                                           \
      vf[ct] = *(const bf16x8*)&Vt[(wave * 64 + ct * 16 + ln) * 32 + g * 8]; \
    const bf16_t* Pr = &Plds[nn & 1][0];                                     \
    bf16x8 pf[2];                                                            \
    _Pragma("unroll")                                                        \
    for (int it = 0; it < 2; ++it)                                           \
      pf[it] = *(const bf16x8*)&Pr[(it * 16 + ln) * 32 + g * 8];             \
    const bool live = (nn < 127);                                            \
    if (sm && live) LOADK(KN, ((nn + 2) & 127) * 32);                        \
    asm volatile("" ::: "memory");  /* K loads stay BEFORE the stage DMAs */ \
    STAGE((nn + 2) & 3, ((nn * 32 + 64) & (N_PIX - 1)));                     \
    if (sm && live) {                                                        \
      bf16x8 pa0;                                                            \
      softmax_tile32(KU, qf, ones, accsum, pa0);                             \
      PWRITE((nn + 1) & 1, pa0);                                             \
    }                                                                        \
    if (sm) { asm volatile("s_waitcnt vmcnt(6)" ::: "memory"); }             \
    else    { asm volatile("s_waitcnt vmcnt(4)" ::: "memory"); }             \
    asm volatile("s_waitcnt lgkmcnt(0)" ::: "memory");                       \
    __builtin_amdgcn_s_barrier();                                            \
    asm volatile("" ::: "memory");                                           \
    __builtin_amdgcn_s_setprio(1);                                           \
    _Pragma("unroll")                                                        \
    for (int ct = 0; ct < 4; ++ct) {                                         \
      acc[ct][0] = mfma16(vf[ct], pf[0], acc[ct][0]);                        \
      acc[ct][1] = mfma16(vf[ct], pf[1], acc[ct][1]);                        \
    }                                                                        \
    __builtin_amdgcn_s_setprio(0);                                           \
  }

    for (int n2 = 0; n2 < 64; ++n2) {
        PV_ITER(2 * n2,     kfA, kfB);
        PV_ITER(2 * n2 + 1, kfB, kfA);
    }
#undef PV_ITER

    // publish l_i (accsum rows identical = full j-sum for i = ln)
    if (sm && g == 0) Llds[wave * 16 + ln] = accsum[0];
    __syncthreads();
    const float gam = gamma[0];
    float sc2[2];
#pragma unroll
    for (int it = 0; it < 2; ++it) sc2[it] = gam / Llds[it * 16 + ln];

#pragma unroll
    for (int ct = 0; ct < 4; ++ct)
#pragma unroll
        for (int it = 0; it < 2; ++it)
#pragma unroll
            for (int r = 0; r < 4; ++r) {
                const int c = wave * 64 + ct * 16 + g * 4 + r;
                const int i = i_base + it * 16 + ln;
                const size_t idx = ((size_t)b * CFEAT + c) * N_PIX + i;
                out[idx] = sc2[it] * acc[ct][it][r] + features[idx];
            }
#undef STAGE
#undef LOADK
#undef PWRITE
}

// ---------------------------------------------------------------------------
extern "C" void kernel_launch(void* const* d_in, const int* in_sizes, int n_in,
                              void* d_out, int out_size, void* d_ws, size_t ws_size,
                              hipStream_t stream) {
    const float* features   = (const float*)d_in[0];
    const float* conditions = (const float*)d_in[1];
    const float* Wq  = (const float*)d_in[2];
    const float* bq  = (const float*)d_in[3];
    const float* Wk  = (const float*)d_in[4];
    const float* bk  = (const float*)d_in[5];
    const float* Wv  = (const float*)d_in[6];
    const float* bv  = (const float*)d_in[7];
    const float* gam = (const float*)d_in[8];
    float* out = (float*)d_out;

    // ws (bf16): Qt 1MB | Kt 1MB | V 8MB
    bf16_t* Qt = (bf16_t*)d_ws;
    bf16_t* Kt = Qt + (size_t)NBATCH * N_PIX * CKEY;
    bf16_t* Vw = Kt + (size_t)NBATCH * N_PIX * CKEY;

    proj_kernel<<<dim3(1024, 1, 1), 256, 0, stream>>>(
        Wq, bq, conditions, Wk, bk, features, Wv, bv, Qt, Kt, Vw);
    pv_kernel<<<dim3(128, NBATCH, 1), 256, 0, stream>>>(
        Qt, Kt, Vw, features, gam, out);
}

// Round 8
// 173.006 us; speedup vs baseline: 1.1039x; 1.1039x over previous
//
#include <hip/hip_runtime.h>

typedef __bf16 bf16_t;
typedef __bf16 bf16x2 __attribute__((ext_vector_type(2)));
typedef __bf16 bf16x8 __attribute__((ext_vector_type(8)));
typedef float f32x4 __attribute__((ext_vector_type(4)));
typedef unsigned u32;
typedef unsigned u32x4 __attribute__((ext_vector_type(4)));

#define N_PIX 4096
#define CFEAT 256
#define CKEY 32
#define NBATCH 4

#if __has_builtin(__builtin_amdgcn_exp2f)
#define EXP2(x) __builtin_amdgcn_exp2f(x)
#else
#define EXP2(x) exp2f(x)
#endif

static __device__ __forceinline__ f32x4 mfma16(bf16x8 a, bf16x8 b, f32x4 c) {
    return __builtin_amdgcn_mfma_f32_16x16x32_bf16(a, b, c, 0, 0, 0);
}

// async global->LDS, 16B per lane; LDS dest = wave-uniform base + lane*16
static __device__ __forceinline__ void glds16(const void* g, void* l) {
    __builtin_amdgcn_global_load_lds(
        (const __attribute__((address_space(1))) void*)g,
        (__attribute__((address_space(3))) void*)l, 16, 0, 0);
}

// pack two f32 -> one dword of 2 bf16 (v_cvt_pk_bf16_f32)
static __device__ __forceinline__ u32 pk2(float lo, float hi) {
    bf16x2 t; t[0] = (bf16_t)lo; t[1] = (bf16_t)hi;
    return __builtin_bit_cast(u32, t);
}

// 4-group transpose step (T12)
static __device__ __forceinline__ void xpose4(u32 &x, u32 &y) {
#if __has_builtin(__builtin_amdgcn_permlane32_swap) && __has_builtin(__builtin_amdgcn_permlane16_swap)
    auto r32 = __builtin_amdgcn_permlane32_swap(x, y, false, false);
    auto r16 = __builtin_amdgcn_permlane16_swap(r32[0], r32[1], false, false);
    x = r16[0]; y = r16[1];
#else
    const int lane = threadIdx.x & 63;
    const int g = lane >> 4, ln = lane & 15;
    const int i0 = ln + ((g & 1) << 5);
    const int i2 = i0 + 16;
    u32 xs0 = (u32)__shfl((int)x, i0), ys0 = (u32)__shfl((int)y, i0);
    u32 xs2 = (u32)__shfl((int)x, i2), ys2 = (u32)__shfl((int)y, i2);
    x = (g < 2) ? xs0 : ys0;
    y = (g < 2) ? xs2 : ys2;
#endif
}

// S^T tile (64 j x 16 i) -> exp2 -> in-register P fragments; l-sum via ones-MFMA.
// (v1-verified code)
static __device__ __forceinline__ void softmax_tile(
    const bf16x8 kf[4], bf16x8 qf, bf16x8 ones,
    f32x4 &accsum, bf16x8 &pa0, bf16x8 &pa1)
{
    f32x4 zero = {0.f, 0.f, 0.f, 0.f};
    f32x4 st[4];
#pragma unroll
    for (int jt = 0; jt < 4; ++jt) st[jt] = mfma16(kf[jt], qf, zero);
    float ex[16];
#pragma unroll
    for (int jt = 0; jt < 4; ++jt)
#pragma unroll
        for (int r = 0; r < 4; ++r) ex[jt * 4 + r] = EXP2(st[jt][r]);
    u32 a0 = pk2(ex[0],  ex[1]),  a1 = pk2(ex[2],  ex[3]);
    u32 b0 = pk2(ex[4],  ex[5]),  b1 = pk2(ex[6],  ex[7]);
    u32 c0 = pk2(ex[8],  ex[9]),  c1 = pk2(ex[10], ex[11]);
    u32 d0 = pk2(ex[12], ex[13]), d1 = pk2(ex[14], ex[15]);
    xpose4(a0, b0); xpose4(a1, b1);
    xpose4(c0, d0); xpose4(c1, d1);
    u32x4 w0 = {a0, a1, b0, b1};
    u32x4 w1 = {c0, c1, d0, d1};
    pa0 = __builtin_bit_cast(bf16x8, w0);
    pa1 = __builtin_bit_cast(bf16x8, w1);
    accsum = mfma16(ones, pa0, accsum);
    accsum = mfma16(ones, pa1, accsum);
}

// ---------------------------------------------------------------------------
// proj_kernel (R4-verified, unchanged): Qt/Kt (transposed bf16, Q pre-scaled
// log2e) and V (bf16 [c][n]).
// ---------------------------------------------------------------------------
__global__ __launch_bounds__(256) void proj_kernel(
    const float* __restrict__ Wq, const float* __restrict__ bq, const float* __restrict__ cond,
    const float* __restrict__ Wk, const float* __restrict__ bk, const float* __restrict__ feat,
    const float* __restrict__ Wv, const float* __restrict__ bv,
    bf16_t* __restrict__ Qt, bf16_t* __restrict__ Kt, bf16_t* __restrict__ Vv)
{
    __shared__ __attribute__((aligned(16))) bf16_t T[64][40];  // QK repack, +8 pad
    const int lane = threadIdx.x & 63, wave = threadIdx.x >> 6;
    const int g = lane >> 4, ln = lane & 15;
    const int bid = blockIdx.x;
    f32x4 zero = {0.f, 0.f, 0.f, 0.f};

    if (bid < 512) {
        const bool isK = (bid >= 256);
        const int idx = bid & 255;
        const int xt = idx & 63;
        const int b  = idx >> 6;
        const float* W    = isK ? Wk : Wq;
        const float* bias = isK ? bk : bq;
        const float* X  = (isK ? feat : cond) + (size_t)b * CFEAT * N_PIX;
        bf16_t*      Yt = (isK ? Kt : Qt) + (size_t)b * N_PIX * CKEY;
        const float qscale = isK ? 1.0f : 1.4426950408889634f;  // log2(e) into Q

        const int m_base = (wave & 1) * 16;
        const int n_loc  = (wave >> 1) * 32;
        const int n_base = xt * 64 + n_loc;

        f32x4 acc[2] = {zero, zero};
        for (int k0 = 0; k0 < CFEAT; k0 += 32) {
            bf16x8 a;
            const float* wp = W + (size_t)(m_base + ln) * CFEAT + k0 + g * 8;
#pragma unroll
            for (int j = 0; j < 8; ++j) a[j] = (bf16_t)wp[j];
#pragma unroll
            for (int nt = 0; nt < 2; ++nt) {
                const float* xp = X + (size_t)(k0 + g * 8) * N_PIX + n_base + nt * 16 + ln;
                bf16x8 bfr;
#pragma unroll
                for (int j = 0; j < 8; ++j) bfr[j] = (bf16_t)xp[(size_t)j * N_PIX];
                acc[nt] = mfma16(a, bfr, acc[nt]);
            }
        }
#pragma unroll
        for (int nt = 0; nt < 2; ++nt)
#pragma unroll
            for (int r = 0; r < 4; ++r) {
                const int ck = m_base + g * 4 + r;
                T[n_loc + nt * 16 + ln][ck] = (bf16_t)((acc[nt][r] + bias[ck]) * qscale);
            }
        __syncthreads();
        const int n  = threadIdx.x >> 2;
        const int sg = threadIdx.x & 3;
        bf16x8 row = *(const bf16x8*)&T[n][sg * 8];
        *(bf16x8*)&Yt[(size_t)(xt * 64 + n) * CKEY + sg * 8] = row;
    } else {
        const int idx = bid - 512;
        const int xt = idx & 127;
        const int b  = idx >> 7;
        const int n_base = xt * 32;
        const int c_wave = wave * 64;
        const float* Xb = feat + (size_t)b * CFEAT * N_PIX;
        bf16_t*      Vb = Vv + (size_t)b * CFEAT * N_PIX;

        f32x4 acc[4][2];
#pragma unroll
        for (int mt = 0; mt < 4; ++mt) { acc[mt][0] = zero; acc[mt][1] = zero; }

        for (int k0 = 0; k0 < CFEAT; k0 += 32) {
            bf16x8 bfr[2];
#pragma unroll
            for (int nt = 0; nt < 2; ++nt) {
                const float* xp = Xb + (size_t)(k0 + g * 8) * N_PIX + n_base + nt * 16 + ln;
#pragma unroll
                for (int j = 0; j < 8; ++j) bfr[nt][j] = (bf16_t)xp[(size_t)j * N_PIX];
            }
#pragma unroll
            for (int mt = 0; mt < 4; ++mt) {
                const float* wp = Wv + (size_t)(c_wave + mt * 16 + ln) * CFEAT + k0 + g * 8;
                bf16x8 a;
#pragma unroll
                for (int j = 0; j < 8; ++j) a[j] = (bf16_t)wp[j];
                acc[mt][0] = mfma16(a, bfr[0], acc[mt][0]);
                acc[mt][1] = mfma16(a, bfr[1], acc[mt][1]);
            }
        }
#pragma unroll
        for (int mt = 0; mt < 4; ++mt)
#pragma unroll
            for (int nt = 0; nt < 2; ++nt)
#pragma unroll
                for (int r = 0; r < 4; ++r) {
                    const int m = c_wave + mt * 16 + g * 4 + r;
                    const int n = n_base + nt * 16 + ln;
                    Vb[(size_t)m * N_PIX + n] = (bf16_t)(acc[mt][nt][r] + bv[m]);
                }
    }
}

// ---------------------------------------------------------------------------
// pv v5: 4-wave producer/consumer, j-tile 64 (64 iters), 2 blocks/CU.
//   - block = 256c x 32i. waves 0-1 (sm): softmax 16i x 64j each -> P ping-
//     pong [32i][64j] (128-B rows, XOR-8 swizzle — v3-proven conflict-free).
//   - all 4 waves PV a private 64c slice: 8 V-frag + 4 P-frag b128 reads,
//     16 MFMA per iter. V LDS [256c][64j], 128-B rows, XOR-8 (v3-proven).
//   - ring-2 V (2 x 32KB): stage(n+1) issued at iter-n top (buf published
//     free by barrier(n-1)), retired at iter-n fence. sm: stage4 then K4,
//     fence vmcnt(4) keeps K(n+2) in flight. pv: stage12, fence vmcnt(0)
//     (drain hidden by the co-resident block — the point of 2/CU).
//   - batch-local XCD swizzle: f%8 -> batch pair, so V(b) (2MB) stays in
//     one XCD's 4MB L2 (cuts the ~20MB L2-thrash overfetch seen in R6).
// LDS 72.3 KB -> 2 blocks/CU; grid 512 = exactly 2/CU.
// ---------------------------------------------------------------------------
__global__ __launch_bounds__(256, 2) void pv_kernel(
    const bf16_t* __restrict__ Qt, const bf16_t* __restrict__ Kt,
    const bf16_t* __restrict__ V,
    const float* __restrict__ features, const float* __restrict__ gamma,
    float* __restrict__ out)
{
    __shared__ __attribute__((aligned(16))) bf16_t Vlds[2][16384];  // 2 x 32KB
    __shared__ __attribute__((aligned(16))) bf16_t Plds[2][2048];   // 2 x 4KB
    __shared__ float Llds[32];

    const int lane = threadIdx.x & 63, wave = threadIdx.x >> 6;  // 0..3
    const int g = lane >> 4, ln = lane & 15;
    // XCD-batch swizzle: f%8 = {2b, 2b+1} -> batch b's 128 blocks on 2 XCDs
    const int f = blockIdx.x;
    const int b = (f & 7) >> 1;
    const int i_tile = (f & 1) + 2 * (f >> 3);
    const int i_base = i_tile * 32;
    const bool sm = (wave < 2);

    const bf16_t* Qb = Qt + (size_t)b * N_PIX * CKEY;
    const bf16_t* Kb = Kt + (size_t)b * N_PIX * CKEY;
    const bf16_t* Vb = V + (size_t)b * CFEAT * N_PIX;

    // staging map (v3-proven): slot s in [0,2048): c = s>>3, jslot = (s&7)^(c&7)
    // sm waves: 4 slots (s = q*128 + wave*64 + lane, q<4)     -> [0,512)
    // pv waves: 12 slots (s = 512 + q*128 + (wave-2)*64+lane) -> [512,2048)
    const int nq = sm ? 4 : 12;
    const int sbase = sm ? (wave * 64 + lane) : (512 + (wave - 2) * 64 + lane);
    const bf16_t* vgp[12];
#pragma unroll
    for (int q = 0; q < 12; ++q) {
        const int s = sbase + (q < nq ? q : 0) * 128;
        const int sc = s >> 3, sj = (s & 7) ^ (sc & 7);
        vgp[q] = Vb + (size_t)sc * N_PIX + sj * 8;
    }

#define STAGE(BUF, JOFF)                                                      \
    if (sm) {                                                                 \
        _Pragma("unroll") for (int q = 0; q < 4; ++q)                         \
            glds16(vgp[q] + (JOFF), &Vlds[BUF][(sbase + q * 128) * 8]);       \
    } else {                                                                  \
        _Pragma("unroll") for (int q = 0; q < 12; ++q)                        \
            glds16(vgp[q] + (JOFF), &Vlds[BUF][(sbase + q * 128) * 8]);       \
    }

#define LOADK(DST, JQ)                                                        \
    { _Pragma("unroll") for (int jt = 0; jt < 4; ++jt)                        \
        DST[jt] = *(const bf16x8*)&Kb[(size_t)((JQ) + jt * 16 + ln) * CKEY + g * 8]; }

    // P [32i][64j], 128-B rows, XOR-8 granule swizzle (v3-proven)
#define PWRITE(SLOT, PA0, PA1)                                                \
    { const int ir = wave * 16 + ln;                                          \
      char* Pw = (char*)&Plds[SLOT][0] + ir * 128;                            \
      *(bf16x8*)(Pw + ((g)     ^ (ir & 7)) * 16) = PA0;                       \
      *(bf16x8*)(Pw + ((4 + g) ^ (ir & 7)) * 16) = PA1; }

    bf16x8 qf = {};
    if (sm) qf = *(const bf16x8*)&Qb[(size_t)(i_base + wave * 16 + ln) * CKEY + g * 8];

    bf16x8 ones;
#pragma unroll
    for (int j = 0; j < 8; ++j) ones[j] = (bf16_t)1.0f;

    f32x4 zero = {0.f, 0.f, 0.f, 0.f};
    f32x4 acc[4][2];
#pragma unroll
    for (int ct = 0; ct < 4; ++ct) { acc[ct][0] = zero; acc[ct][1] = zero; }
    f32x4 accsum = zero;

    bf16x8 kfA[4], kfB[4];

    // ---------------- prologue: P(0) -> slot0; stage V(0); kfA = K(1) -------
    {
        bf16x8 kf0[4];
        if (sm) LOADK(kf0, 0);
        asm volatile("" ::: "memory");
        STAGE(0, 0);
        if (sm) {
            bf16x8 pa0, pa1;
            softmax_tile(kf0, qf, ones, accsum, pa0, pa1);
            PWRITE(0, pa0, pa1);
            LOADK(kfA, 64);
        }
        asm volatile("s_waitcnt vmcnt(0)" ::: "memory");
        asm volatile("s_waitcnt lgkmcnt(0)" ::: "memory");
        __builtin_amdgcn_s_barrier();
        asm volatile("" ::: "memory");
    }

// iter n: ds_read V(n)+P(n) frags; stage V(n+1) into buf (n+1)&1 (last read
// at iter n-1, published free by barrier(n-1)); sm: K(n+2) issue + softmax
// K(n+1) -> P(n+1); fence (sm vmcnt(4) keeps K / pv vmcnt(0)) + lgkm(0) +
// barrier; PV(n) MFMAs.
#define PV_ITER(NN, KU, KN)                                                   \
  {                                                                           \
    const int nn = (NN);                                                      \
    const bf16_t* Vt = &Vlds[nn & 1][0];                                      \
    bf16x8 vf[8];                                                             \
    _Pragma("unroll")                                                         \
    for (int ct = 0; ct < 4; ++ct)                                            \
      _Pragma("unroll")                                                       \
      for (int s = 0; s < 2; ++s) {                                           \
        const int c = wave * 64 + ct * 16 + ln;                               \
        vf[ct * 2 + s] = *(const bf16x8*)&Vt[(c * 8 + ((s * 4 + g) ^ (c & 7))) * 8]; \
      }                                                                       \
    const char* Pr = (const char*)&Plds[nn & 1][0];                           \
    bf16x8 pf[4];                                                             \
    _Pragma("unroll")                                                         \
    for (int it = 0; it < 2; ++it)                                            \
      _Pragma("unroll")                                                       \
      for (int s = 0; s < 2; ++s)                                             \
        pf[it * 2 + s] = *(const bf16x8*)(Pr + (it * 16 + ln) * 128           \
                           + ((s * 4 + g) ^ (ln & 7)) * 16);                  \
    STAGE((nn + 1) & 1, (((nn + 1) & 63) * 64));                              \
    const bool live = (nn < 63);                                              \
    if (sm && live) {                                                         \
      LOADK(KN, ((nn + 2) & 63) * 64);                                        \
      bf16x8 pa0, pa1;                                                        \
      softmax_tile(KU, qf, ones, accsum, pa0, pa1);                           \
      PWRITE((nn + 1) & 1, pa0, pa1);                                         \
    }                                                                         \
    if (sm) { asm volatile("s_waitcnt vmcnt(4)" ::: "memory"); }              \
    else    { asm volatile("s_waitcnt vmcnt(0)" ::: "memory"); }              \
    asm volatile("s_waitcnt lgkmcnt(0)" ::: "memory");                        \
    __builtin_amdgcn_s_barrier();                                             \
    asm volatile("" ::: "memory");                                            \
    __builtin_amdgcn_s_setprio(1);                                            \
    _Pragma("unroll")                                                         \
    for (int ct = 0; ct < 4; ++ct)                                            \
      _Pragma("unroll")                                                       \
      for (int it = 0; it < 2; ++it) {                                        \
        acc[ct][it] = mfma16(vf[ct * 2 + 0], pf[it * 2 + 0], acc[ct][it]);    \
        acc[ct][it] = mfma16(vf[ct * 2 + 1], pf[it * 2 + 1], acc[ct][it]);    \
      }                                                                       \
    __builtin_amdgcn_s_setprio(0);                                            \
  }

    for (int n2 = 0; n2 < 32; ++n2) {
        PV_ITER(2 * n2,     kfA, kfB);
        PV_ITER(2 * n2 + 1, kfB, kfA);
    }
#undef PV_ITER

    // publish l_i (accsum rows identical = full 64-tile j-sum for i = ln)
    if (sm && g == 0) Llds[wave * 16 + ln] = accsum[0];
    __syncthreads();
    const float gam = gamma[0];
    float sc2[2];
#pragma unroll
    for (int it = 0; it < 2; ++it) sc2[it] = gam / Llds[it * 16 + ln];

#pragma unroll
    for (int ct = 0; ct < 4; ++ct)
#pragma unroll
        for (int it = 0; it < 2; ++it)
#pragma unroll
            for (int r = 0; r < 4; ++r) {
                const int c = wave * 64 + ct * 16 + g * 4 + r;
                const int i = i_base + it * 16 + ln;
                const size_t idx = ((size_t)b * CFEAT + c) * N_PIX + i;
                out[idx] = sc2[it] * acc[ct][it][r] + features[idx];
            }
#undef STAGE
#undef LOADK
#undef PWRITE
}

// ---------------------------------------------------------------------------
extern "C" void kernel_launch(void* const* d_in, const int* in_sizes, int n_in,
                              void* d_out, int out_size, void* d_ws, size_t ws_size,
                              hipStream_t stream) {
    const float* features   = (const float*)d_in[0];
    const float* conditions = (const float*)d_in[1];
    const float* Wq  = (const float*)d_in[2];
    const float* bq  = (const float*)d_in[3];
    const float* Wk  = (const float*)d_in[4];
    const float* bk  = (const float*)d_in[5];
    const float* Wv  = (const float*)d_in[6];
    const float* bv  = (const float*)d_in[7];
    const float* gam = (const float*)d_in[8];
    float* out = (float*)d_out;

    // ws (bf16): Qt 1MB | Kt 1MB | V 8MB
    bf16_t* Qt = (bf16_t*)d_ws;
    bf16_t* Kt = Qt + (size_t)NBATCH * N_PIX * CKEY;
    bf16_t* Vw = Kt + (size_t)NBATCH * N_PIX * CKEY;

    proj_kernel<<<dim3(1024, 1, 1), 256, 0, stream>>>(
        Wq, bq, conditions, Wk, bk, features, Wv, bv, Qt, Kt, Vw);
    pv_kernel<<<dim3(512, 1, 1), 256, 0, stream>>>(
        Qt, Kt, Vw, features, gam, out);
}

// Round 9
// 169.207 us; speedup vs baseline: 1.1287x; 1.0225x over previous
//
#include <hip/hip_runtime.h>

typedef __bf16 bf16_t;
typedef __bf16 bf16x2 __attribute__((ext_vector_type(2)));
typedef __bf16 bf16x8 __attribute__((ext_vector_type(8)));
typedef float f32x4 __attribute__((ext_vector_type(4)));
typedef unsigned u32;
typedef unsigned u32x4 __attribute__((ext_vector_type(4)));

#define N_PIX 4096
#define CFEAT 256
#define CKEY 32
#define NBATCH 4

#if __has_builtin(__builtin_amdgcn_exp2f)
#define EXP2(x) __builtin_amdgcn_exp2f(x)
#else
#define EXP2(x) exp2f(x)
#endif

static __device__ __forceinline__ f32x4 mfma16(bf16x8 a, bf16x8 b, f32x4 c) {
    return __builtin_amdgcn_mfma_f32_16x16x32_bf16(a, b, c, 0, 0, 0);
}

// async global->LDS, 16B per lane; LDS dest = wave-uniform base + lane*16
static __device__ __forceinline__ void glds16(const void* g, void* l) {
    __builtin_amdgcn_global_load_lds(
        (const __attribute__((address_space(1))) void*)g,
        (__attribute__((address_space(3))) void*)l, 16, 0, 0);
}

// pack two f32 -> one dword of 2 bf16 (v_cvt_pk_bf16_f32)
static __device__ __forceinline__ u32 pk2(float lo, float hi) {
    bf16x2 t; t[0] = (bf16_t)lo; t[1] = (bf16_t)hi;
    return __builtin_bit_cast(u32, t);
}

// 4-group transpose step (T12)
static __device__ __forceinline__ void xpose4(u32 &x, u32 &y) {
#if __has_builtin(__builtin_amdgcn_permlane32_swap) && __has_builtin(__builtin_amdgcn_permlane16_swap)
    auto r32 = __builtin_amdgcn_permlane32_swap(x, y, false, false);
    auto r16 = __builtin_amdgcn_permlane16_swap(r32[0], r32[1], false, false);
    x = r16[0]; y = r16[1];
#else
    const int lane = threadIdx.x & 63;
    const int g = lane >> 4, ln = lane & 15;
    const int i0 = ln + ((g & 1) << 5);
    const int i2 = i0 + 16;
    u32 xs0 = (u32)__shfl((int)x, i0), ys0 = (u32)__shfl((int)y, i0);
    u32 xs2 = (u32)__shfl((int)x, i2), ys2 = (u32)__shfl((int)y, i2);
    x = (g < 2) ? xs0 : ys0;
    y = (g < 2) ? xs2 : ys2;
#endif
}

// S^T tile (64 j x 16 i) -> exp2 -> in-register P fragments; l-sum via ones-MFMA.
static __device__ __forceinline__ void softmax_tile(
    const bf16x8 kf[4], bf16x8 qf, bf16x8 ones,
    f32x4 &accsum, bf16x8 &pa0, bf16x8 &pa1)
{
    f32x4 zero = {0.f, 0.f, 0.f, 0.f};
    f32x4 st[4];
#pragma unroll
    for (int jt = 0; jt < 4; ++jt) st[jt] = mfma16(kf[jt], qf, zero);
    float ex[16];
#pragma unroll
    for (int jt = 0; jt < 4; ++jt)
#pragma unroll
        for (int r = 0; r < 4; ++r) ex[jt * 4 + r] = EXP2(st[jt][r]);
    u32 a0 = pk2(ex[0],  ex[1]),  a1 = pk2(ex[2],  ex[3]);
    u32 b0 = pk2(ex[4],  ex[5]),  b1 = pk2(ex[6],  ex[7]);
    u32 c0 = pk2(ex[8],  ex[9]),  c1 = pk2(ex[10], ex[11]);
    u32 d0 = pk2(ex[12], ex[13]), d1 = pk2(ex[14], ex[15]);
    xpose4(a0, b0); xpose4(a1, b1);
    xpose4(c0, d0); xpose4(c1, d1);
    u32x4 w0 = {a0, a1, b0, b1};
    u32x4 w1 = {c0, c1, d0, d1};
    pa0 = __builtin_bit_cast(bf16x8, w0);
    pa1 = __builtin_bit_cast(bf16x8, w1);
    accsum = mfma16(ones, pa0, accsum);
    accsum = mfma16(ones, pa1, accsum);
}

// ---------------------------------------------------------------------------
// proj_kernel (R4-verified, unchanged): Qt/Kt (transposed bf16, Q pre-scaled
// log2e) and V (bf16 [c][n]).
// ---------------------------------------------------------------------------
__global__ __launch_bounds__(256) void proj_kernel(
    const float* __restrict__ Wq, const float* __restrict__ bq, const float* __restrict__ cond,
    const float* __restrict__ Wk, const float* __restrict__ bk, const float* __restrict__ feat,
    const float* __restrict__ Wv, const float* __restrict__ bv,
    bf16_t* __restrict__ Qt, bf16_t* __restrict__ Kt, bf16_t* __restrict__ Vv)
{
    __shared__ __attribute__((aligned(16))) bf16_t T[64][40];  // QK repack, +8 pad
    const int lane = threadIdx.x & 63, wave = threadIdx.x >> 6;
    const int g = lane >> 4, ln = lane & 15;
    const int bid = blockIdx.x;
    f32x4 zero = {0.f, 0.f, 0.f, 0.f};

    if (bid < 512) {
        const bool isK = (bid >= 256);
        const int idx = bid & 255;
        const int xt = idx & 63;
        const int b  = idx >> 6;
        const float* W    = isK ? Wk : Wq;
        const float* bias = isK ? bk : bq;
        const float* X  = (isK ? feat : cond) + (size_t)b * CFEAT * N_PIX;
        bf16_t*      Yt = (isK ? Kt : Qt) + (size_t)b * N_PIX * CKEY;
        const float qscale = isK ? 1.0f : 1.4426950408889634f;  // log2(e) into Q

        const int m_base = (wave & 1) * 16;
        const int n_loc  = (wave >> 1) * 32;
        const int n_base = xt * 64 + n_loc;

        f32x4 acc[2] = {zero, zero};
        for (int k0 = 0; k0 < CFEAT; k0 += 32) {
            bf16x8 a;
            const float* wp = W + (size_t)(m_base + ln) * CFEAT + k0 + g * 8;
#pragma unroll
            for (int j = 0; j < 8; ++j) a[j] = (bf16_t)wp[j];
#pragma unroll
            for (int nt = 0; nt < 2; ++nt) {
                const float* xp = X + (size_t)(k0 + g * 8) * N_PIX + n_base + nt * 16 + ln;
                bf16x8 bfr;
#pragma unroll
                for (int j = 0; j < 8; ++j) bfr[j] = (bf16_t)xp[(size_t)j * N_PIX];
                acc[nt] = mfma16(a, bfr, acc[nt]);
            }
        }
#pragma unroll
        for (int nt = 0; nt < 2; ++nt)
#pragma unroll
            for (int r = 0; r < 4; ++r) {
                const int ck = m_base + g * 4 + r;
                T[n_loc + nt * 16 + ln][ck] = (bf16_t)((acc[nt][r] + bias[ck]) * qscale);
            }
        __syncthreads();
        const int n  = threadIdx.x >> 2;
        const int sg = threadIdx.x & 3;
        bf16x8 row = *(const bf16x8*)&T[n][sg * 8];
        *(bf16x8*)&Yt[(size_t)(xt * 64 + n) * CKEY + sg * 8] = row;
    } else {
        const int idx = bid - 512;
        const int xt = idx & 127;
        const int b  = idx >> 7;
        const int n_base = xt * 32;
        const int c_wave = wave * 64;
        const float* Xb = feat + (size_t)b * CFEAT * N_PIX;
        bf16_t*      Vb = Vv + (size_t)b * CFEAT * N_PIX;

        f32x4 acc[4][2];
#pragma unroll
        for (int mt = 0; mt < 4; ++mt) { acc[mt][0] = zero; acc[mt][1] = zero; }

        for (int k0 = 0; k0 < CFEAT; k0 += 32) {
            bf16x8 bfr[2];
#pragma unroll
            for (int nt = 0; nt < 2; ++nt) {
                const float* xp = Xb + (size_t)(k0 + g * 8) * N_PIX + n_base + nt * 16 + ln;
#pragma unroll
                for (int j = 0; j < 8; ++j) bfr[nt][j] = (bf16_t)xp[(size_t)j * N_PIX];
            }
#pragma unroll
            for (int mt = 0; mt < 4; ++mt) {
                const float* wp = Wv + (size_t)(c_wave + mt * 16 + ln) * CFEAT + k0 + g * 8;
                bf16x8 a;
#pragma unroll
                for (int j = 0; j < 8; ++j) a[j] = (bf16_t)wp[j];
                acc[mt][0] = mfma16(a, bfr[0], acc[mt][0]);
                acc[mt][1] = mfma16(a, bfr[1], acc[mt][1]);
            }
        }
#pragma unroll
        for (int mt = 0; mt < 4; ++mt)
#pragma unroll
            for (int nt = 0; nt < 2; ++nt)
#pragma unroll
                for (int r = 0; r < 4; ++r) {
                    const int m = c_wave + mt * 16 + g * 4 + r;
                    const int n = n_base + nt * 16 + ln;
                    Vb[(size_t)m * N_PIX + n] = (bf16_t)(acc[mt][nt][r] + bv[m]);
                }
    }
}

// ---------------------------------------------------------------------------
// pv v6: v5 + stage distance 2 within ring-2 (the fence never drains a
// fresh DMA):
//   - iter n stages tile n+2 into buf[n&1] (the buffer JUST read this iter;
//     lgkmcnt(0) after the ds_reads guards the same-wave WAR; cross-wave
//     margin = DMA flight (~250cyc) >> post-barrier read completion).
//   - fences: sm vmcnt(8) (keeps K(n+2)4 + stage(n+2)4), pv vmcnt(12)
//     (keeps stage(n+2)12, retires stage(n+1) issued a FULL iter ago ~free).
//   - sm waves: softmax runs concurrently with their V/P ds_reads (no dep;
//     MFMA/trans vs LDS pipes); K loads before STAGE so the implicit K-wait
//     (vmcnt<=8) retires old stages for free.
//   - everything else = v5: 4 waves (2 sm x 16i + 2 pv), 256c x 32i block,
//     j=64, XOR-8 swizzles (0-conflict, verified), XCD batch swizzle,
//     2 blocks/CU (72.3 KB LDS), grid 512.
// ---------------------------------------------------------------------------
__global__ __launch_bounds__(256, 2) void pv_kernel(
    const bf16_t* __restrict__ Qt, const bf16_t* __restrict__ Kt,
    const bf16_t* __restrict__ V,
    const float* __restrict__ features, const float* __restrict__ gamma,
    float* __restrict__ out)
{
    __shared__ __attribute__((aligned(16))) bf16_t Vlds[2][16384];  // 2 x 32KB
    __shared__ __attribute__((aligned(16))) bf16_t Plds[2][2048];   // 2 x 4KB
    __shared__ float Llds[32];

    const int lane = threadIdx.x & 63, wave = threadIdx.x >> 6;  // 0..3
    const int g = lane >> 4, ln = lane & 15;
    // XCD-batch swizzle: f%8 = {2b, 2b+1} -> batch b's 128 blocks on 2 XCDs
    const int f = blockIdx.x;
    const int b = (f & 7) >> 1;
    const int i_tile = (f & 1) + 2 * (f >> 3);
    const int i_base = i_tile * 32;
    const bool sm = (wave < 2);

    const bf16_t* Qb = Qt + (size_t)b * N_PIX * CKEY;
    const bf16_t* Kb = Kt + (size_t)b * N_PIX * CKEY;
    const bf16_t* Vb = V + (size_t)b * CFEAT * N_PIX;

    // staging map (v3-proven): slot s in [0,2048): c = s>>3, jslot = (s&7)^(c&7)
    const int nq = sm ? 4 : 12;
    const int sbase = sm ? (wave * 64 + lane) : (512 + (wave - 2) * 64 + lane);
    const bf16_t* vgp[12];
#pragma unroll
    for (int q = 0; q < 12; ++q) {
        const int s = sbase + (q < nq ? q : 0) * 128;
        const int sc = s >> 3, sj = (s & 7) ^ (sc & 7);
        vgp[q] = Vb + (size_t)sc * N_PIX + sj * 8;
    }

#define STAGE(BUF, JOFF)                                                      \
    if (sm) {                                                                 \
        _Pragma("unroll") for (int q = 0; q < 4; ++q)                         \
            glds16(vgp[q] + (JOFF), &Vlds[BUF][(sbase + q * 128) * 8]);       \
    } else {                                                                  \
        _Pragma("unroll") for (int q = 0; q < 12; ++q)                        \
            glds16(vgp[q] + (JOFF), &Vlds[BUF][(sbase + q * 128) * 8]);       \
    }

#define LOADK(DST, JQ)                                                        \
    { _Pragma("unroll") for (int jt = 0; jt < 4; ++jt)                        \
        DST[jt] = *(const bf16x8*)&Kb[(size_t)((JQ) + jt * 16 + ln) * CKEY + g * 8]; }

    // P [32i][64j], 128-B rows, XOR-8 granule swizzle (v3-proven)
#define PWRITE(SLOT, PA0, PA1)                                                \
    { const int ir = wave * 16 + ln;                                          \
      char* Pw = (char*)&Plds[SLOT][0] + ir * 128;                            \
      *(bf16x8*)(Pw + ((g)     ^ (ir & 7)) * 16) = PA0;                       \
      *(bf16x8*)(Pw + ((4 + g) ^ (ir & 7)) * 16) = PA1; }

    bf16x8 qf = {};
    if (sm) qf = *(const bf16x8*)&Qb[(size_t)(i_base + wave * 16 + ln) * CKEY + g * 8];

    bf16x8 ones;
#pragma unroll
    for (int j = 0; j < 8; ++j) ones[j] = (bf16_t)1.0f;

    f32x4 zero = {0.f, 0.f, 0.f, 0.f};
    f32x4 acc[4][2];
#pragma unroll
    for (int ct = 0; ct < 4; ++ct) { acc[ct][0] = zero; acc[ct][1] = zero; }
    f32x4 accsum = zero;

    bf16x8 kfA[4], kfB[4];

    // -------- prologue: stage V(0)->buf0, V(1)->buf1; P(0); kfA = K(1) ------
    {
        bf16x8 kf0[4];
        if (sm) LOADK(kf0, 0);
        asm volatile("" ::: "memory");
        STAGE(0, 0);
        STAGE(1, 64);
        if (sm) {
            bf16x8 pa0, pa1;
            softmax_tile(kf0, qf, ones, accsum, pa0, pa1);
            PWRITE(0, pa0, pa1);
            LOADK(kfA, 64);
        }
        asm volatile("s_waitcnt vmcnt(0)" ::: "memory");
        asm volatile("s_waitcnt lgkmcnt(0)" ::: "memory");
        __builtin_amdgcn_s_barrier();
        asm volatile("" ::: "memory");
    }

// iter n: ds_read V(n)+P(n) frags from buf[n&1]; sm: K(n+2) + softmax
// K(n+1) -> P(n+1); lgkm(0) (read-before-overwrite guard + P publish);
// stage V(n+2) into buf[n&1]; fence sm vmcnt(8) / pv vmcnt(12); barrier;
// PV(n) MFMAs.
#define PV_ITER(NN, KU, KN)                                                   \
  {                                                                           \
    const int nn = (NN);                                                      \
    const bf16_t* Vt = &Vlds[nn & 1][0];                                      \
    bf16x8 vf[8];                                                             \
    _Pragma("unroll")                                                         \
    for (int ct = 0; ct < 4; ++ct)                                            \
      _Pragma("unroll")                                                       \
      for (int s = 0; s < 2; ++s) {                                           \
        const int c = wave * 64 + ct * 16 + ln;                               \
        vf[ct * 2 + s] = *(const bf16x8*)&Vt[(c * 8 + ((s * 4 + g) ^ (c & 7))) * 8]; \
      }                                                                       \
    const char* Pr = (const char*)&Plds[nn & 1][0];                           \
    bf16x8 pf[4];                                                             \
    _Pragma("unroll")                                                         \
    for (int it = 0; it < 2; ++it)                                            \
      _Pragma("unroll")                                                       \
      for (int s = 0; s < 2; ++s)                                             \
        pf[it * 2 + s] = *(const bf16x8*)(Pr + (it * 16 + ln) * 128           \
                           + ((s * 4 + g) ^ (ln & 7)) * 16);                  \
    const bool live = (nn < 63);                                              \
    if (sm && live) {                                                         \
      LOADK(KN, ((nn + 2) & 63) * 64);                                        \
      bf16x8 pa0, pa1;                                                        \
      softmax_tile(KU, qf, ones, accsum, pa0, pa1);                           \
      PWRITE((nn + 1) & 1, pa0, pa1);                                         \
    }                                                                         \
    asm volatile("s_waitcnt lgkmcnt(0)" ::: "memory");                        \
    STAGE((nn) & 1, (((nn + 2) & 63) * 64));                                  \
    if (sm) { asm volatile("s_waitcnt vmcnt(8)" ::: "memory"); }              \
    else    { asm volatile("s_waitcnt vmcnt(12)" ::: "memory"); }             \
    __builtin_amdgcn_s_barrier();                                             \
    asm volatile("" ::: "memory");                                            \
    __builtin_amdgcn_s_setprio(1);                                            \
    _Pragma("unroll")                                                         \
    for (int ct = 0; ct < 4; ++ct)                                            \
      _Pragma("unroll")                                                       \
      for (int it = 0; it < 2; ++it) {                                        \
        acc[ct][it] = mfma16(vf[ct * 2 + 0], pf[it * 2 + 0], acc[ct][it]);    \
        acc[ct][it] = mfma16(vf[ct * 2 + 1], pf[it * 2 + 1], acc[ct][it]);    \
      }                                                                       \
    __builtin_amdgcn_s_setprio(0);                                            \
  }

    for (int n2 = 0; n2 < 32; ++n2) {
        PV_ITER(2 * n2,     kfA, kfB);
        PV_ITER(2 * n2 + 1, kfB, kfA);
    }
#undef PV_ITER

    // publish l_i (accsum rows identical = full 64-tile j-sum for i = ln)
    if (sm && g == 0) Llds[wave * 16 + ln] = accsum[0];
    __syncthreads();
    const float gam = gamma[0];
    float sc2[2];
#pragma unroll
    for (int it = 0; it < 2; ++it) sc2[it] = gam / Llds[it * 16 + ln];

#pragma unroll
    for (int ct = 0; ct < 4; ++ct)
#pragma unroll
        for (int it = 0; it < 2; ++it)
#pragma unroll
            for (int r = 0; r < 4; ++r) {
                const int c = wave * 64 + ct * 16 + g * 4 + r;
                const int i = i_base + it * 16 + ln;
                const size_t idx = ((size_t)b * CFEAT + c) * N_PIX + i;
                out[idx] = sc2[it] * acc[ct][it][r] + features[idx];
            }
#undef STAGE
#undef LOADK
#undef PWRITE
}

// ---------------------------------------------------------------------------
extern "C" void kernel_launch(void* const* d_in, const int* in_sizes, int n_in,
                              void* d_out, int out_size, void* d_ws, size_t ws_size,
                              hipStream_t stream) {
    const float* features   = (const float*)d_in[0];
    const float* conditions = (const float*)d_in[1];
    const float* Wq  = (const float*)d_in[2];
    const float* bq  = (const float*)d_in[3];
    const float* Wk  = (const float*)d_in[4];
    const float* bk  = (const float*)d_in[5];
    const float* Wv  = (const float*)d_in[6];
    const float* bv  = (const float*)d_in[7];
    const float* gam = (const float*)d_in[8];
    float* out = (float*)d_out;

    // ws (bf16): Qt 1MB | Kt 1MB | V 8MB
    bf16_t* Qt = (bf16_t*)d_ws;
    bf16_t* Kt = Qt + (size_t)NBATCH * N_PIX * CKEY;
    bf16_t* Vw = Kt + (size_t)NBATCH * N_PIX * CKEY;

    proj_kernel<<<dim3(1024, 1, 1), 256, 0, stream>>>(
        Wq, bq, conditions, Wk, bk, features, Wv, bv, Qt, Kt, Vw);
    pv_kernel<<<dim3(512, 1, 1), 256, 0, stream>>>(
        Qt, Kt, Vw, features, gam, out);
}